// Round 6
// baseline (407.495 us; speedup 1.0000x reference)
//
#include <hip/hip_runtime.h>
#include <stdint.h>

typedef unsigned long long u64;
typedef unsigned short ushort_t;
#define NPTS 4096
#define KNN 20

using bf16x8 = __attribute__((ext_vector_type(8))) short;
using f32x4  = __attribute__((ext_vector_type(4))) float;

__device__ __forceinline__ unsigned orderbits(float f) {
  unsigned u = __float_as_uint(f);
  return ((int)u < 0) ? ~u : (u | 0x80000000u);
}

__device__ __forceinline__ ushort_t f2bf(float f) {  // RNE, finite inputs
  unsigned u = __float_as_uint(f);
  u += 0x7fffu + ((u >> 16) & 1u);
  return (ushort_t)(u >> 16);
}

__device__ __forceinline__ u64 shflxor64(u64 v, int m) {
  unsigned lo = __shfl_xor((unsigned)(v & 0xffffffffull), m, 64);
  unsigned hi = __shfl_xor((unsigned)(v >> 32), m, 64);
  return (((u64)hi) << 32) | lo;
}

// exact reference-association distance; the UNIQUE d-computation (determinism)
__device__ __forceinline__ float dist_exact(float4 q, float4 a) {
  float inner = __fadd_rn(__fadd_rn(__fmul_rn(q.x, a.x), __fmul_rn(q.y, a.y)),
                          __fmul_rn(q.z, a.z));
  return __fadd_rn(__fsub_rn(q.w, __fmul_rn(2.0f, inner)), a.w);
}
// monotone in d; sqrt spreads buckets so boundary bucket stays small even for
// outlier query points (no saturation hole: covers d^2 < 64)
__device__ __forceinline__ unsigned bucket_of(float d) {
  float s = __fmul_rn(sqrtf(fmaxf(d, 0.f)), 128.0f);
  unsigned u = (unsigned)s;
  return min(u, 1023u);
}

// ---------------- Kernel 0: xT4[b][m] = (x,y,z,||x||^2) ---------------------
__global__ __launch_bounds__(256) void prep_kernel(const float* __restrict__ x,
                                                   float4* __restrict__ xT4) {
  int i = blockIdx.x * 256 + threadIdx.x;  // 32768
  int b = i >> 12, m = i & 4095;
  const float* xb = x + (size_t)b * 3 * NPTS;
  float a0 = xb[m], a1 = xb[NPTS + m], a2 = xb[2 * NPTS + m];
  float sq = __fadd_rn(__fadd_rn(__fmul_rn(a0, a0), __fmul_rn(a1, a1)),
                       __fmul_rn(a2, a2));
  xT4[i] = make_float4(a0, a1, a2, sq);
}

// ---------------- Kernel 1: exact KNN, single-eval radix select -------------
// 4 points/block; d evaluated once per pair; u16 bucket keys held in REGISTERS
// (no LDS cost). Loop 2 classifies from keys (2-3 VALU); boundary-bucket
// members (~2-32) recompute exact d and resolve on (orderbits, idx).
#define NB 1024
#define PPB 4
#define CCAP 128
__global__ __launch_bounds__(256) void knn_kernel(const float4* __restrict__ xT4,
                                                  int* __restrict__ knn_out) {
  __shared__ unsigned hist[PPB * NB];   // 16 KB
  __shared__ u64 cand[PPB * CCAP];      // 4 KB
  __shared__ unsigned sB[PPB], sCnt[PPB], sCand[PPB];

  const int tid = threadIdx.x;
  const int bid = blockIdx.x;           // 8192
  const int b = bid >> 10;
  const int n0 = (bid & 1023) * PPB;
  const float4* xb4 = xT4 + (size_t)b * NPTS;

  float4 q[PPB];
#pragma unroll
  for (int p = 0; p < PPB; ++p) q[p] = xb4[n0 + p];

  for (int i = tid; i < PPB * NB; i += 256) hist[i] = 0;
  if (tid < PPB) { sCnt[tid] = 0; sCand[tid] = 0; }
  __syncthreads();

  // loop 1: single evaluation, u16 keys -> registers, histogram
  unsigned kL[16], kH[16];
#pragma unroll 4
  for (int it = 0; it < 16; ++it) {
    const int m = it * 256 + tid;
    float4 a = xb4[m];
    unsigned bk0 = bucket_of(dist_exact(q[0], a));
    unsigned bk1 = bucket_of(dist_exact(q[1], a));
    unsigned bk2 = bucket_of(dist_exact(q[2], a));
    unsigned bk3 = bucket_of(dist_exact(q[3], a));
    atomicAdd(&hist[0 * NB + bk0], 1u);
    atomicAdd(&hist[1 * NB + bk1], 1u);
    atomicAdd(&hist[2 * NB + bk2], 1u);
    atomicAdd(&hist[3 * NB + bk3], 1u);
    kL[it] = bk0 | (bk1 << 16);
    kH[it] = bk2 | (bk3 << 16);
  }
  __syncthreads();

  // scan: wave wv owns point wv's 1024-bucket hist (16 buckets/lane)
  const int lane = tid & 63, wv = tid >> 6;
  {
    unsigned h[16]; unsigned local = 0;
    const int hb = wv * NB + lane * 16;
#pragma unroll
    for (int j = 0; j < 16; ++j) { h[j] = hist[hb + j]; local += h[j]; }
    unsigned incl = local;
    for (int off = 1; off < 64; off <<= 1) {
      unsigned v = __shfl_up(incl, off, 64);
      if (lane >= off) incl += v;
    }
    unsigned excl = incl - local;
    if (excl < KNN && incl >= KNN) {       // exactly one lane
      unsigned cum = excl;
#pragma unroll
      for (int j = 0; j < 16; ++j) {
        if (cum + h[j] >= KNN) { sB[wv] = lane * 16 + j; break; }
        cum += h[j];
      }
    }
  }
  __syncthreads();

  const unsigned B0 = sB[0], B1 = sB[1], B2 = sB[2], B3 = sB[3];
  // loop 2: classify from register keys; rare exact recompute at boundary
  for (int it = 0; it < 16; ++it) {
    const int m = it * 256 + tid;
    unsigned ks[PPB];
    ks[0] = kL[it] & 0xffffu; ks[1] = kL[it] >> 16;
    ks[2] = kH[it] & 0xffffu; ks[3] = kH[it] >> 16;
    unsigned Bs[PPB] = {B0, B1, B2, B3};
#pragma unroll
    for (int p = 0; p < PPB; ++p) {
      if (ks[p] < Bs[p]) {
        unsigned s = atomicAdd(&sCnt[p], 1u);
        knn_out[((size_t)((b << 12) + n0 + p)) * KNN + s] = m;
      } else if (ks[p] == Bs[p]) {
        float d = dist_exact(q[p], xb4[m]);
        unsigned s = atomicAdd(&sCand[p], 1u);
        if (s < CCAP) cand[p * CCAP + s] = (((u64)orderbits(d)) << 32) | (unsigned)m;
      }
    }
  }
  __syncthreads();

  // boundary: wave wv extracts (20 - nsel) smallest (key,idx)
  {
    const int nsel = (int)sCnt[wv];
    const int ncand = min((int)sCand[wv], CCAP);
    const int ntake = KNN - nsel;
    const size_t base = ((size_t)((b << 12) + n0 + wv)) * KNN;
    volatile u64* vc = &cand[wv * CCAP];
    for (int t = 0; t < ntake; ++t) {
      u64 mk = ~0ull;
      for (int i = lane; i < ncand; i += 64) { u64 v = vc[i]; if (v < mk) mk = v; }
      for (int off = 32; off; off >>= 1) { u64 o = shflxor64(mk, off); if (o < mk) mk = o; }
      if (lane == 0) knn_out[base + nsel + t] = (int)(unsigned)(mk & 0xffffffffull);
      for (int i = lane; i < ncand; i += 64) { if (vc[i] == mk) vc[i] = ~0ull; }
    }
  }
}

// ---------------- Kernel 2: fused edge MLP 6->64->128 (MFMA) + max over K ---
// h1 LDS shrunk to 24 rows/point (40 KB total with w2) -> 4 blocks/CU.
// Tile-1 A-frag reads overrun into w2 region of the SAME smem array: the
// garbage rows map to C rows discarded by the quad==0 mask (C row m depends
// only on A row m).
__global__ __launch_bounds__(256, 4) void edge_fused(
    const float4* __restrict__ xT4, const int* __restrict__ knn,
    const float* __restrict__ W1, const float* __restrict__ b1,
    const ushort_t* __restrict__ w2B, const float* __restrict__ b2,
    ushort_t* __restrict__ hT) {
  __shared__ __align__(16) ushort_t smem[8 * 24 * 64 + 128 * 64];  // 40 KB
  ushort_t* h1S = smem;                 // 8 pts x 24 rows x 64 ch (rows 20..23 garbage)
  ushort_t* w2S = smem + 8 * 24 * 64;   // 128 x 64, chunk-XOR swizzled
  const int tid = threadIdx.x;
  const int lane = tid & 63, wv = tid >> 6;
  const int ln = lane & 15, quad = lane >> 4;

  // cooperative W2 stage: chunk c of row stored at c^(row&7)
  {
    const int4* wg = (const int4*)w2B;
#pragma unroll
    for (int j = 0; j < 4; ++j) {
      int q = j * 256 + tid;
      int row = q >> 3, c = q & 7;
      ((int4*)w2S)[row * 8 + (c ^ (row & 7))] = wg[q];
    }
  }
  float b2r[8];
#pragma unroll
  for (int n = 0; n < 8; ++n) b2r[n] = b2[n * 16 + ln];

  // ---- stage 1: h1 = relu(W1 @ edge + b1), 2 channels/thread, 20 edges
  {
    const int p = tid >> 5, s5 = tid & 31;
    const int idx = blockIdx.x * 8 + p;
    const int b = idx >> 12, n = idx & 4095;
    const float4* xb4 = xT4 + ((size_t)b << 12);
    const float4 c4 = xb4[n];
    const int c0 = 2 * s5;
    float w1a[6], w1b[6];
#pragma unroll
    for (int j = 0; j < 6; ++j) {
      w1a[j] = W1[c0 * 6 + j];
      w1b[j] = W1[(c0 + 1) * 6 + j];
    }
    const float b1a = b1[c0], b1b = b1[c0 + 1];
    const int kbase = idx * KNN;
    unsigned* h1d = (unsigned*)h1S;
#pragma unroll 4
    for (int k = 0; k < KNN; ++k) {
      int nb = knn[kbase + k];
      float4 a4 = xb4[nb];
      float e3 = a4.x - c4.x, e4 = a4.y - c4.y, e5 = a4.z - c4.z;
      float za = b1a, zb = b1b;
      za = fmaf(w1a[0], c4.x, za); zb = fmaf(w1b[0], c4.x, zb);
      za = fmaf(w1a[1], c4.y, za); zb = fmaf(w1b[1], c4.y, zb);
      za = fmaf(w1a[2], c4.z, za); zb = fmaf(w1b[2], c4.z, zb);
      za = fmaf(w1a[3], e3, za);   zb = fmaf(w1b[3], e3, zb);
      za = fmaf(w1a[4], e4, za);   zb = fmaf(w1b[4], e4, zb);
      za = fmaf(w1a[5], e5, za);   zb = fmaf(w1b[5], e5, zb);
      unsigned pk = (unsigned)f2bf(fmaxf(za, 0.f)) |
                    ((unsigned)f2bf(fmaxf(zb, 0.f)) << 16);
      int row = p * 24 + k;
      int dw = row * 32 + (((s5 >> 2) ^ (row & 7)) << 2) + (s5 & 3);
      h1d[dw] = pk;
    }
  }
  __syncthreads();

  // B-fragments from swizzled LDS
  bf16x8 Bf[8][2];
#pragma unroll
  for (int n = 0; n < 8; ++n)
#pragma unroll
    for (int s = 0; s < 2; ++s) {
      int row = n * 16 + ln;
      Bf[n][s] = *(const bf16x8*)&w2S[row * 64 + (((s * 4 + quad) ^ (ln & 7)) << 3)];
    }

  // ---- stage 2: per wave, points {2w, 2w+1}
  const int base_idx = blockIdx.x * 8;
#pragma unroll
  for (int pi = 0; pi < 2; ++pi) {
    const int ps = wv * 2 + pi;
    const int sw = ln & 7;
    float vmax[8];
    {  // tile 0: edge rows 0..15 (all real)
      const int row = ps * 24 + ln;
      bf16x8 A0 = *(const bf16x8*)&h1S[row * 64 + (((0 + quad) ^ sw) << 3)];
      bf16x8 A1 = *(const bf16x8*)&h1S[row * 64 + (((4 + quad) ^ sw) << 3)];
      f32x4 acc;
#pragma unroll
      for (int n = 0; n < 8; ++n) {
        acc = (f32x4){0.f, 0.f, 0.f, 0.f};
        acc = __builtin_amdgcn_mfma_f32_16x16x32_bf16(A0, Bf[n][0], acc, 0, 0, 0);
        acc = __builtin_amdgcn_mfma_f32_16x16x32_bf16(A1, Bf[n][1], acc, 0, 0, 0);
        vmax[n] = fmaxf(fmaxf(acc[0], acc[1]), fmaxf(acc[2], acc[3]));
      }
    }
    {  // tile 1: edge rows 16..; real only 16..19 => quad==0 C rows
      const int row = ps * 24 + 16 + ln;
      bf16x8 A0 = *(const bf16x8*)&h1S[row * 64 + (((0 + quad) ^ sw) << 3)];
      bf16x8 A1 = *(const bf16x8*)&h1S[row * 64 + (((4 + quad) ^ sw) << 3)];
      f32x4 acc;
#pragma unroll
      for (int n = 0; n < 8; ++n) {
        acc = (f32x4){0.f, 0.f, 0.f, 0.f};
        acc = __builtin_amdgcn_mfma_f32_16x16x32_bf16(A0, Bf[n][0], acc, 0, 0, 0);
        acc = __builtin_amdgcn_mfma_f32_16x16x32_bf16(A1, Bf[n][1], acc, 0, 0, 0);
        float v1 = (quad == 0)
                       ? fmaxf(fmaxf(acc[0], acc[1]), fmaxf(acc[2], acc[3]))
                       : -INFINITY;
        vmax[n] = fmaxf(vmax[n], v1);
      }
    }
    const int gidx = base_idx + ps;
#pragma unroll
    for (int n = 0; n < 8; ++n) {
      float v = vmax[n];
      v = fmaxf(v, __shfl_xor(v, 16, 64));
      v = fmaxf(v, __shfl_xor(v, 32, 64));
      if (quad == 0) {
        hT[(size_t)gidx * 128 + n * 16 + ln] = f2bf(fmaxf(v + b2r[n], 0.f));
      }
    }
  }
}

// ---------------- Kernel 2.5: Wi and W2 fp32 -> bf16 ------------------------
__global__ __launch_bounds__(256) void convert_weights(
    const float* __restrict__ Wi, const float* __restrict__ W2,
    ushort_t* __restrict__ wiB, ushort_t* __restrict__ w2B) {
  int i = blockIdx.x * 256 + threadIdx.x;  // 131072 grid
  if (i < 131072) wiB[i] = f2bf(Wi[i]);
  if (i < 8192)   w2B[i] = f2bf(W2[i]);
}

// ---------------- Kernel 3: 128->1024 via bf16 MFMA + relu + max over N -----
#define LDP 136
__global__ __launch_bounds__(256, 2) void inception_mfma(
    const ushort_t* __restrict__ hT, const ushort_t* __restrict__ wiB,
    const float* __restrict__ bi, unsigned* __restrict__ g) {
  __shared__ __align__(16) ushort_t hS[128 * LDP];
  __shared__ __align__(16) ushort_t wS[128 * LDP];
  const int tid = threadIdx.x;
  const int b = blockIdx.z;
  const int m0 = blockIdx.x * 128;
  const int n0 = blockIdx.y * 128;

  const ushort_t* hg = hT + ((size_t)b * NPTS + m0) * 128;
  const ushort_t* wg = wiB + (size_t)n0 * 128;
#pragma unroll
  for (int i = 0; i < 8; ++i) {
    int chunk = i * 256 + tid;
    int row = chunk >> 4, c = chunk & 15;
    *(int4*)&hS[row * LDP + c * 8] = *(const int4*)&hg[row * 128 + c * 8];
    *(int4*)&wS[row * LDP + c * 8] = *(const int4*)&wg[row * 128 + c * 8];
  }
  __syncthreads();

  const int lane = tid & 63, wid = tid >> 6;
  const int ln = lane & 15, quad = lane >> 4;
  const int mw = (wid >> 1) * 64, nw = (wid & 1) * 64;

  f32x4 acc[4][4];
#pragma unroll
  for (int mi = 0; mi < 4; ++mi)
#pragma unroll
    for (int ni = 0; ni < 4; ++ni) acc[mi][ni] = (f32x4){0.f, 0.f, 0.f, 0.f};

#pragma unroll
  for (int kk = 0; kk < 4; ++kk) {
    bf16x8 af[4], bfr[4];
    const int ko = kk * 32 + quad * 8;
#pragma unroll
    for (int mi = 0; mi < 4; ++mi)
      af[mi] = *(const bf16x8*)&hS[(mw + mi * 16 + ln) * LDP + ko];
#pragma unroll
    for (int ni = 0; ni < 4; ++ni)
      bfr[ni] = *(const bf16x8*)&wS[(nw + ni * 16 + ln) * LDP + ko];
#pragma unroll
    for (int mi = 0; mi < 4; ++mi)
#pragma unroll
      for (int ni = 0; ni < 4; ++ni)
        acc[mi][ni] = __builtin_amdgcn_mfma_f32_16x16x32_bf16(
            af[mi], bfr[ni], acc[mi][ni], 0, 0, 0);
  }

#pragma unroll
  for (int ni = 0; ni < 4; ++ni) {
    float v = acc[0][ni][0];
#pragma unroll
    for (int mi = 0; mi < 4; ++mi)
#pragma unroll
      for (int r = 0; r < 4; ++r) v = fmaxf(v, acc[mi][ni][r]);
    v = fmaxf(v, __shfl_xor(v, 16, 64));
    v = fmaxf(v, __shfl_xor(v, 32, 64));
    if (quad == 0) {
      int o = n0 + nw + ni * 16 + ln;
      float val = fmaxf(v + bi[o], 0.f);
      atomicMax(&g[b * 1024 + o], __float_as_uint(val));
    }
  }
}

// ---------------- Kernel 4: head 1024->512->256->9 + I ----------------------
__global__ __launch_bounds__(512) void head_kernel(
    const unsigned* __restrict__ g, const float* __restrict__ Wg1,
    const float* __restrict__ bg1, const float* __restrict__ Wg2,
    const float* __restrict__ bg2, const float* __restrict__ Wl,
    const float* __restrict__ bl, float* __restrict__ out) {
  __shared__ __align__(16) float gl[1024];
  __shared__ __align__(16) float g1l[512];
  __shared__ __align__(16) float g2l[256];
  const int tid = threadIdx.x;
  const int b = blockIdx.x;
  for (int i = tid; i < 1024; i += 512) gl[i] = __uint_as_float(g[b * 1024 + i]);
  __syncthreads();
  {
    const float4* w = (const float4*)(Wg1 + (size_t)tid * 1024);
    const float4* gv = (const float4*)gl;
    float a0 = bg1[tid], a1 = 0.f, a2 = 0.f, a3 = 0.f;
    for (int j = 0; j < 256; j += 4) {
      float4 w0 = w[j], w1 = w[j+1], w2 = w[j+2], w3 = w[j+3];
      float4 v0 = gv[j], v1 = gv[j+1], v2 = gv[j+2], v3 = gv[j+3];
      a0 = fmaf(w0.x, v0.x, a0); a0 = fmaf(w0.y, v0.y, a0);
      a0 = fmaf(w0.z, v0.z, a0); a0 = fmaf(w0.w, v0.w, a0);
      a1 = fmaf(w1.x, v1.x, a1); a1 = fmaf(w1.y, v1.y, a1);
      a1 = fmaf(w1.z, v1.z, a1); a1 = fmaf(w1.w, v1.w, a1);
      a2 = fmaf(w2.x, v2.x, a2); a2 = fmaf(w2.y, v2.y, a2);
      a2 = fmaf(w2.z, v2.z, a2); a2 = fmaf(w2.w, v2.w, a2);
      a3 = fmaf(w3.x, v3.x, a3); a3 = fmaf(w3.y, v3.y, a3);
      a3 = fmaf(w3.z, v3.z, a3); a3 = fmaf(w3.w, v3.w, a3);
    }
    g1l[tid] = fmaxf((a0 + a1) + (a2 + a3), 0.f);
  }
  __syncthreads();
  if (tid < 256) {
    const float4* w = (const float4*)(Wg2 + (size_t)tid * 512);
    const float4* gv = (const float4*)g1l;
    float a0 = bg2[tid], a1 = 0.f;
    for (int j = 0; j < 128; j += 2) {
      float4 w0 = w[j], w1 = w[j+1];
      float4 v0 = gv[j], v1 = gv[j+1];
      a0 = fmaf(w0.x, v0.x, a0); a0 = fmaf(w0.y, v0.y, a0);
      a0 = fmaf(w0.z, v0.z, a0); a0 = fmaf(w0.w, v0.w, a0);
      a1 = fmaf(w1.x, v1.x, a1); a1 = fmaf(w1.y, v1.y, a1);
      a1 = fmaf(w1.z, v1.z, a1); a1 = fmaf(w1.w, v1.w, a1);
    }
    g2l[tid] = fmaxf(a0 + a1, 0.f);
  }
  __syncthreads();
  if (tid < 9) {
    float acc = bl[tid];
    for (int c = 0; c < 256; ++c) acc = fmaf(Wl[tid * 256 + c], g2l[c], acc);
    if (tid == 0 || tid == 4 || tid == 8) acc += 1.0f;
    out[b * 9 + tid] = acc;
  }
}

extern "C" void kernel_launch(void* const* d_in, const int* in_sizes, int n_in,
                              void* d_out, int out_size, void* d_ws, size_t ws_size,
                              hipStream_t stream) {
  const float* x   = (const float*)d_in[0];
  const float* W1  = (const float*)d_in[1];
  const float* b1  = (const float*)d_in[2];
  const float* W2  = (const float*)d_in[3];
  const float* b2  = (const float*)d_in[4];
  const float* Wi  = (const float*)d_in[5];
  const float* bi  = (const float*)d_in[6];
  const float* Wg1 = (const float*)d_in[7];
  const float* bg1 = (const float*)d_in[8];
  const float* Wg2 = (const float*)d_in[9];
  const float* bg2 = (const float*)d_in[10];
  const float* Wl  = (const float*)d_in[11];
  const float* bl  = (const float*)d_in[12];

  int*       knn = (int*)d_ws;                                   // 2.62 MB @ 0
  ushort_t*  hT  = (ushort_t*)((char*)d_ws + (3u << 20));        // 8 MB bf16
  ushort_t*  wiB = (ushort_t*)((char*)d_ws + (12u << 20));       // 256 KB bf16
  ushort_t*  w2B = (ushort_t*)((char*)d_ws + (12u << 20) + (512u << 10)); // 16 KB
  float4*    xT4 = (float4*)((char*)d_ws + (13u << 20));         // 512 KB
  unsigned*  g   = (unsigned*)((char*)d_ws + (14u << 20));       // 32 KB

  prep_kernel<<<128, 256, 0, stream>>>(x, xT4);
  knn_kernel<<<8 * NPTS / PPB, 256, 0, stream>>>(xT4, knn);
  convert_weights<<<512, 256, 0, stream>>>(Wi, W2, wiB, w2B);
  edge_fused<<<8 * NPTS / 8, 256, 0, stream>>>(xT4, knn, W1, b1, w2B, b2, hT);
  hipMemsetAsync(g, 0, 8 * 1024 * sizeof(unsigned), stream);
  inception_mfma<<<dim3(32, 8, 8), 256, 0, stream>>>(hT, wiB, bi, g);
  head_kernel<<<8, 512, 0, stream>>>(g, Wg1, bg1, Wg2, bg2, Wl, bl, (float*)d_out);
}

// Round 7
// 327.659 us; speedup vs baseline: 1.2437x; 1.2437x over previous
//
#include <hip/hip_runtime.h>
#include <stdint.h>

typedef unsigned long long u64;
typedef unsigned short ushort_t;
#define NPTS 4096
#define KNN 20

using bf16x8 = __attribute__((ext_vector_type(8))) short;
using f32x4  = __attribute__((ext_vector_type(4))) float;
using f32x2  = __attribute__((ext_vector_type(2))) float;

__device__ __forceinline__ unsigned orderbits(float f) {
  unsigned u = __float_as_uint(f);
  return ((int)u < 0) ? ~u : (u | 0x80000000u);
}

__device__ __forceinline__ ushort_t f2bf(float f) {  // RNE, finite inputs
  unsigned u = __float_as_uint(f);
  u += 0x7fffu + ((u >> 16) & 1u);
  return (ushort_t)(u >> 16);
}

__device__ __forceinline__ u64 shflxor64(u64 v, int m) {
  unsigned lo = __shfl_xor((unsigned)(v & 0xffffffffull), m, 64);
  unsigned hi = __shfl_xor((unsigned)(v >> 32), m, 64);
  return (((u64)hi) << 32) | lo;
}

// canonical reference-association distance (UNIQUE rounding sequence)
__device__ __forceinline__ float dist_exact(float4 q, float4 a) {
  float inner = __fadd_rn(__fadd_rn(__fmul_rn(q.x, a.x), __fmul_rn(q.y, a.y)),
                          __fmul_rn(q.z, a.z));
  return __fadd_rn(__fsub_rn(q.w, __fmul_rn(2.0f, inner)), a.w);
}

// packed 2-query distance: v_pk_mul/add_f32, contract(off) => each half is
// bit-identical to dist_exact (same ops, same association, RN, no fma)
__device__ __forceinline__ f32x2 dist2(f32x2 qx, f32x2 qy, f32x2 qz, f32x2 qw,
                                       float4 a) {
#pragma clang fp contract(off)
  f32x2 ax = {a.x, a.x}, ay = {a.y, a.y}, az = {a.z, a.z}, aw = {a.w, a.w};
  f32x2 t0 = qx * ax;
  f32x2 t1 = qy * ay;
  f32x2 t2 = qz * az;
  f32x2 inner = (t0 + t1) + t2;
  f32x2 two = {2.0f, 2.0f};
  return (qw - two * inner) + aw;
}

// monotone bucket: positive fp32 bits are integer-monotone; log-spacing gives
// fine resolution at small d (boundary bucket ~1-2 members). 4 VALU, no sqrt.
// Covers d in [2^-12, 2^20); below -> bucket 0 (exact fallback handles).
__device__ __forceinline__ unsigned bucket_of(float d) {
  unsigned bits = __float_as_uint(fmaxf(d, 0.f));
  int t = (int)(bits >> 18) - 3680;            // 3680 = bits(2^-12)>>18
  return (unsigned)min(max(t, 0), 1023);
}

// ---------------- Kernel 0: xT4[b][m] = (x,y,z,||x||^2) ---------------------
__global__ __launch_bounds__(256) void prep_kernel(const float* __restrict__ x,
                                                   float4* __restrict__ xT4) {
  int i = blockIdx.x * 256 + threadIdx.x;  // 32768
  int b = i >> 12, m = i & 4095;
  const float* xb = x + (size_t)b * 3 * NPTS;
  float a0 = xb[m], a1 = xb[NPTS + m], a2 = xb[2 * NPTS + m];
  float sq = __fadd_rn(__fadd_rn(__fmul_rn(a0, a0), __fmul_rn(a1, a1)),
                       __fmul_rn(a2, a2));
  xT4[i] = make_float4(a0, a1, a2, sq);
}

// ---------------- Kernel 1: exact KNN, single-eval radix select -------------
#define NB 1024
#define PPB 4
#define CCAP 128
__global__ __launch_bounds__(256) void knn_kernel(const float4* __restrict__ xT4,
                                                  int* __restrict__ knn_out) {
  __shared__ unsigned hist[PPB * NB];   // 16 KB
  __shared__ u64 cand[PPB * CCAP];      // 4 KB
  __shared__ unsigned sB[PPB], sCnt[PPB], sCand[PPB];

  const int tid = threadIdx.x;
  const int bid = blockIdx.x;           // 8192
  const int b = bid >> 10;
  const int n0 = (bid & 1023) * PPB;
  const float4* xb4 = xT4 + (size_t)b * NPTS;

  float4 q[PPB];
#pragma unroll
  for (int p = 0; p < PPB; ++p) q[p] = xb4[n0 + p];
  const f32x2 qx01 = {q[0].x, q[1].x}, qy01 = {q[0].y, q[1].y},
              qz01 = {q[0].z, q[1].z}, qw01 = {q[0].w, q[1].w};
  const f32x2 qx23 = {q[2].x, q[3].x}, qy23 = {q[2].y, q[3].y},
              qz23 = {q[2].z, q[3].z}, qw23 = {q[2].w, q[3].w};

  for (int i = tid; i < PPB * NB; i += 256) hist[i] = 0;
  if (tid < PPB) { sCnt[tid] = 0; sCand[tid] = 0; }
  __syncthreads();

  // loop 1: single evaluation (packed), u16 keys -> registers, histogram
  unsigned kL[16], kH[16];
#pragma unroll 4
  for (int it = 0; it < 16; ++it) {
    const int m = it * 256 + tid;
    float4 a = xb4[m];
    f32x2 d01 = dist2(qx01, qy01, qz01, qw01, a);
    f32x2 d23 = dist2(qx23, qy23, qz23, qw23, a);
    unsigned bk0 = bucket_of(d01[0]);
    unsigned bk1 = bucket_of(d01[1]);
    unsigned bk2 = bucket_of(d23[0]);
    unsigned bk3 = bucket_of(d23[1]);
    atomicAdd(&hist[0 * NB + bk0], 1u);
    atomicAdd(&hist[1 * NB + bk1], 1u);
    atomicAdd(&hist[2 * NB + bk2], 1u);
    atomicAdd(&hist[3 * NB + bk3], 1u);
    kL[it] = bk0 | (bk1 << 16);
    kH[it] = bk2 | (bk3 << 16);
  }
  __syncthreads();

  // scan: wave wv owns point wv's 1024-bucket hist (16 buckets/lane)
  const int lane = tid & 63, wv = tid >> 6;
  {
    unsigned h[16]; unsigned local = 0;
    const int hb = wv * NB + lane * 16;
#pragma unroll
    for (int j = 0; j < 16; ++j) { h[j] = hist[hb + j]; local += h[j]; }
    unsigned incl = local;
    for (int off = 1; off < 64; off <<= 1) {
      unsigned v = __shfl_up(incl, off, 64);
      if (lane >= off) incl += v;
    }
    unsigned excl = incl - local;
    if (excl < KNN && incl >= KNN) {       // exactly one lane
      unsigned cum = excl;
#pragma unroll
      for (int j = 0; j < 16; ++j) {
        if (cum + h[j] >= KNN) { sB[wv] = lane * 16 + j; break; }
        cum += h[j];
      }
    }
  }
  __syncthreads();

  const unsigned B0 = sB[0], B1 = sB[1], B2 = sB[2], B3 = sB[3];
  // loop 2: classify from register keys; exact recompute only at boundary
  for (int it = 0; it < 16; ++it) {
    const int m = it * 256 + tid;
    unsigned ks[PPB];
    ks[0] = kL[it] & 0xffffu; ks[1] = kL[it] >> 16;
    ks[2] = kH[it] & 0xffffu; ks[3] = kH[it] >> 16;
    unsigned Bs[PPB] = {B0, B1, B2, B3};
#pragma unroll
    for (int p = 0; p < PPB; ++p) {
      if (ks[p] < Bs[p]) {
        unsigned s = atomicAdd(&sCnt[p], 1u);
        knn_out[((size_t)((b << 12) + n0 + p)) * KNN + s] = m;
      } else if (ks[p] == Bs[p]) {
        float d = dist_exact(q[p], xb4[m]);
        unsigned s = atomicAdd(&sCand[p], 1u);
        if (s < CCAP) cand[p * CCAP + s] = (((u64)orderbits(d)) << 32) | (unsigned)m;
      }
    }
  }
  __syncthreads();

  // boundary: wave wv extracts (20 - nsel) smallest (key,idx)
  {
    const int nsel = (int)sCnt[wv];
    const int ncand = min((int)sCand[wv], CCAP);
    const int ntake = KNN - nsel;
    const size_t base = ((size_t)((b << 12) + n0 + wv)) * KNN;
    volatile u64* vc = &cand[wv * CCAP];
    for (int t = 0; t < ntake; ++t) {
      u64 mk = ~0ull;
      for (int i = lane; i < ncand; i += 64) { u64 v = vc[i]; if (v < mk) mk = v; }
      for (int off = 32; off; off >>= 1) { u64 o = shflxor64(mk, off); if (o < mk) mk = o; }
      if (lane == 0) knn_out[base + nsel + t] = (int)(unsigned)(mk & 0xffffffffull);
      for (int i = lane; i < ncand; i += 64) { if (vc[i] == mk) vc[i] = ~0ull; }
    }
  }
}

// ---------------- Kernel 2: fused edge MLP 6->64->128 (MFMA) + max over K ---
// r4 configuration (best measured): 32 rows/point, 48 KB LDS, 2 blocks/CU.
__global__ __launch_bounds__(256, 2) void edge_fused(
    const float4* __restrict__ xT4, const int* __restrict__ knn,
    const float* __restrict__ W1, const float* __restrict__ b1,
    const ushort_t* __restrict__ w2B, const float* __restrict__ b2,
    ushort_t* __restrict__ hT) {
  __shared__ __align__(16) ushort_t h1S[8 * 32 * 64];  // 32 KB
  __shared__ __align__(16) ushort_t w2S[128 * 64];     // 16 KB, swizzled
  const int tid = threadIdx.x;
  const int lane = tid & 63, wv = tid >> 6;
  const int ln = lane & 15, quad = lane >> 4;

  // cooperative W2 stage: chunk c of row stored at c^(row&7)
  {
    const int4* wg = (const int4*)w2B;
#pragma unroll
    for (int j = 0; j < 4; ++j) {
      int q = j * 256 + tid;
      int row = q >> 3, c = q & 7;
      ((int4*)w2S)[row * 8 + (c ^ (row & 7))] = wg[q];
    }
  }
  float b2r[8];
#pragma unroll
  for (int n = 0; n < 8; ++n) b2r[n] = b2[n * 16 + ln];

  // ---- stage 1: h1 = relu(W1 @ edge + b1), 2 channels/thread, 20 edges
  {
    const int p = tid >> 5, s5 = tid & 31;
    const int idx = blockIdx.x * 8 + p;
    const int b = idx >> 12, n = idx & 4095;
    const float4* xb4 = xT4 + ((size_t)b << 12);
    const float4 c4 = xb4[n];
    const int c0 = 2 * s5;
    float w1a[6], w1b[6];
#pragma unroll
    for (int j = 0; j < 6; ++j) {
      w1a[j] = W1[c0 * 6 + j];
      w1b[j] = W1[(c0 + 1) * 6 + j];
    }
    const float b1a = b1[c0], b1b = b1[c0 + 1];
    const int kbase = idx * KNN;
    unsigned* h1d = (unsigned*)h1S;
#pragma unroll 4
    for (int k = 0; k < KNN; ++k) {
      int nb = knn[kbase + k];
      float4 a4 = xb4[nb];
      float e3 = a4.x - c4.x, e4 = a4.y - c4.y, e5 = a4.z - c4.z;
      float za = b1a, zb = b1b;
      za = fmaf(w1a[0], c4.x, za); zb = fmaf(w1b[0], c4.x, zb);
      za = fmaf(w1a[1], c4.y, za); zb = fmaf(w1b[1], c4.y, zb);
      za = fmaf(w1a[2], c4.z, za); zb = fmaf(w1b[2], c4.z, zb);
      za = fmaf(w1a[3], e3, za);   zb = fmaf(w1b[3], e3, zb);
      za = fmaf(w1a[4], e4, za);   zb = fmaf(w1b[4], e4, zb);
      za = fmaf(w1a[5], e5, za);   zb = fmaf(w1b[5], e5, zb);
      unsigned pk = (unsigned)f2bf(fmaxf(za, 0.f)) |
                    ((unsigned)f2bf(fmaxf(zb, 0.f)) << 16);
      int row = p * 32 + k;
      int dw = row * 32 + (((s5 >> 2) ^ (row & 7)) << 2) + (s5 & 3);
      h1d[dw] = pk;
    }
  }
  __syncthreads();

  // B-fragments from swizzled LDS
  bf16x8 Bf[8][2];
#pragma unroll
  for (int n = 0; n < 8; ++n)
#pragma unroll
    for (int s = 0; s < 2; ++s) {
      int row = n * 16 + ln;
      Bf[n][s] = *(const bf16x8*)&w2S[row * 64 + (((s * 4 + quad) ^ (ln & 7)) << 3)];
    }

  // ---- stage 2: per wave, points {2w, 2w+1}; rows 20..31 garbage -> mask
  const int base_idx = blockIdx.x * 8;
#pragma unroll
  for (int pi = 0; pi < 2; ++pi) {
    const int ps = wv * 2 + pi;
    const int sw = ln & 7;
    float vmax[8];
    {  // tile 0: edge rows 0..15 (all real)
      const int row = ps * 32 + ln;
      bf16x8 A0 = *(const bf16x8*)&h1S[row * 64 + (((0 + quad) ^ sw) << 3)];
      bf16x8 A1 = *(const bf16x8*)&h1S[row * 64 + (((4 + quad) ^ sw) << 3)];
      f32x4 acc;
#pragma unroll
      for (int n = 0; n < 8; ++n) {
        acc = (f32x4){0.f, 0.f, 0.f, 0.f};
        acc = __builtin_amdgcn_mfma_f32_16x16x32_bf16(A0, Bf[n][0], acc, 0, 0, 0);
        acc = __builtin_amdgcn_mfma_f32_16x16x32_bf16(A1, Bf[n][1], acc, 0, 0, 0);
        vmax[n] = fmaxf(fmaxf(acc[0], acc[1]), fmaxf(acc[2], acc[3]));
      }
    }
    {  // tile 1: edge rows 16..31; real only 16..19 => quad==0 C rows
      const int row = ps * 32 + 16 + ln;
      bf16x8 A0 = *(const bf16x8*)&h1S[row * 64 + (((0 + quad) ^ sw) << 3)];
      bf16x8 A1 = *(const bf16x8*)&h1S[row * 64 + (((4 + quad) ^ sw) << 3)];
      f32x4 acc;
#pragma unroll
      for (int n = 0; n < 8; ++n) {
        acc = (f32x4){0.f, 0.f, 0.f, 0.f};
        acc = __builtin_amdgcn_mfma_f32_16x16x32_bf16(A0, Bf[n][0], acc, 0, 0, 0);
        acc = __builtin_amdgcn_mfma_f32_16x16x32_bf16(A1, Bf[n][1], acc, 0, 0, 0);
        float v1 = (quad == 0)
                       ? fmaxf(fmaxf(acc[0], acc[1]), fmaxf(acc[2], acc[3]))
                       : -INFINITY;
        vmax[n] = fmaxf(vmax[n], v1);
      }
    }
    const int gidx = base_idx + ps;
#pragma unroll
    for (int n = 0; n < 8; ++n) {
      float v = vmax[n];
      v = fmaxf(v, __shfl_xor(v, 16, 64));
      v = fmaxf(v, __shfl_xor(v, 32, 64));
      if (quad == 0) {
        hT[(size_t)gidx * 128 + n * 16 + ln] = f2bf(fmaxf(v + b2r[n], 0.f));
      }
    }
  }
}

// ---------------- Kernel 2.5: Wi and W2 fp32 -> bf16 ------------------------
__global__ __launch_bounds__(256) void convert_weights(
    const float* __restrict__ Wi, const float* __restrict__ W2,
    ushort_t* __restrict__ wiB, ushort_t* __restrict__ w2B) {
  int i = blockIdx.x * 256 + threadIdx.x;  // 131072 grid
  if (i < 131072) wiB[i] = f2bf(Wi[i]);
  if (i < 8192)   w2B[i] = f2bf(W2[i]);
}

// ---------------- Kernel 3: 128->1024 via bf16 MFMA + relu + max over N -----
#define LDP 136
__global__ __launch_bounds__(256, 2) void inception_mfma(
    const ushort_t* __restrict__ hT, const ushort_t* __restrict__ wiB,
    const float* __restrict__ bi, unsigned* __restrict__ g) {
  __shared__ __align__(16) ushort_t hS[128 * LDP];
  __shared__ __align__(16) ushort_t wS[128 * LDP];
  const int tid = threadIdx.x;
  const int b = blockIdx.z;
  const int m0 = blockIdx.x * 128;
  const int n0 = blockIdx.y * 128;

  const ushort_t* hg = hT + ((size_t)b * NPTS + m0) * 128;
  const ushort_t* wg = wiB + (size_t)n0 * 128;
#pragma unroll
  for (int i = 0; i < 8; ++i) {
    int chunk = i * 256 + tid;
    int row = chunk >> 4, c = chunk & 15;
    *(int4*)&hS[row * LDP + c * 8] = *(const int4*)&hg[row * 128 + c * 8];
    *(int4*)&wS[row * LDP + c * 8] = *(const int4*)&wg[row * 128 + c * 8];
  }
  __syncthreads();

  const int lane = tid & 63, wid = tid >> 6;
  const int ln = lane & 15, quad = lane >> 4;
  const int mw = (wid >> 1) * 64, nw = (wid & 1) * 64;

  f32x4 acc[4][4];
#pragma unroll
  for (int mi = 0; mi < 4; ++mi)
#pragma unroll
    for (int ni = 0; ni < 4; ++ni) acc[mi][ni] = (f32x4){0.f, 0.f, 0.f, 0.f};

#pragma unroll
  for (int kk = 0; kk < 4; ++kk) {
    bf16x8 af[4], bfr[4];
    const int ko = kk * 32 + quad * 8;
#pragma unroll
    for (int mi = 0; mi < 4; ++mi)
      af[mi] = *(const bf16x8*)&hS[(mw + mi * 16 + ln) * LDP + ko];
#pragma unroll
    for (int ni = 0; ni < 4; ++ni)
      bfr[ni] = *(const bf16x8*)&wS[(nw + ni * 16 + ln) * LDP + ko];
#pragma unroll
    for (int mi = 0; mi < 4; ++mi)
#pragma unroll
      for (int ni = 0; ni < 4; ++ni)
        acc[mi][ni] = __builtin_amdgcn_mfma_f32_16x16x32_bf16(
            af[mi], bfr[ni], acc[mi][ni], 0, 0, 0);
  }

#pragma unroll
  for (int ni = 0; ni < 4; ++ni) {
    float v = acc[0][ni][0];
#pragma unroll
    for (int mi = 0; mi < 4; ++mi)
#pragma unroll
      for (int r = 0; r < 4; ++r) v = fmaxf(v, acc[mi][ni][r]);
    v = fmaxf(v, __shfl_xor(v, 16, 64));
    v = fmaxf(v, __shfl_xor(v, 32, 64));
    if (quad == 0) {
      int o = n0 + nw + ni * 16 + ln;
      float val = fmaxf(v + bi[o], 0.f);
      atomicMax(&g[b * 1024 + o], __float_as_uint(val));
    }
  }
}

// ---------------- Kernel 4: head 1024->512->256->9 + I ----------------------
__global__ __launch_bounds__(512) void head_kernel(
    const unsigned* __restrict__ g, const float* __restrict__ Wg1,
    const float* __restrict__ bg1, const float* __restrict__ Wg2,
    const float* __restrict__ bg2, const float* __restrict__ Wl,
    const float* __restrict__ bl, float* __restrict__ out) {
  __shared__ __align__(16) float gl[1024];
  __shared__ __align__(16) float g1l[512];
  __shared__ __align__(16) float g2l[256];
  const int tid = threadIdx.x;
  const int b = blockIdx.x;
  for (int i = tid; i < 1024; i += 512) gl[i] = __uint_as_float(g[b * 1024 + i]);
  __syncthreads();
  {
    const float4* w = (const float4*)(Wg1 + (size_t)tid * 1024);
    const float4* gv = (const float4*)gl;
    float a0 = bg1[tid], a1 = 0.f, a2 = 0.f, a3 = 0.f;
    for (int j = 0; j < 256; j += 4) {
      float4 w0 = w[j], w1 = w[j+1], w2 = w[j+2], w3 = w[j+3];
      float4 v0 = gv[j], v1 = gv[j+1], v2 = gv[j+2], v3 = gv[j+3];
      a0 = fmaf(w0.x, v0.x, a0); a0 = fmaf(w0.y, v0.y, a0);
      a0 = fmaf(w0.z, v0.z, a0); a0 = fmaf(w0.w, v0.w, a0);
      a1 = fmaf(w1.x, v1.x, a1); a1 = fmaf(w1.y, v1.y, a1);
      a1 = fmaf(w1.z, v1.z, a1); a1 = fmaf(w1.w, v1.w, a1);
      a2 = fmaf(w2.x, v2.x, a2); a2 = fmaf(w2.y, v2.y, a2);
      a2 = fmaf(w2.z, v2.z, a2); a2 = fmaf(w2.w, v2.w, a2);
      a3 = fmaf(w3.x, v3.x, a3); a3 = fmaf(w3.y, v3.y, a3);
      a3 = fmaf(w3.z, v3.z, a3); a3 = fmaf(w3.w, v3.w, a3);
    }
    g1l[tid] = fmaxf((a0 + a1) + (a2 + a3), 0.f);
  }
  __syncthreads();
  if (tid < 256) {
    const float4* w = (const float4*)(Wg2 + (size_t)tid * 512);
    const float4* gv = (const float4*)g1l;
    float a0 = bg2[tid], a1 = 0.f;
    for (int j = 0; j < 128; j += 2) {
      float4 w0 = w[j], w1 = w[j+1];
      float4 v0 = gv[j], v1 = gv[j+1];
      a0 = fmaf(w0.x, v0.x, a0); a0 = fmaf(w0.y, v0.y, a0);
      a0 = fmaf(w0.z, v0.z, a0); a0 = fmaf(w0.w, v0.w, a0);
      a1 = fmaf(w1.x, v1.x, a1); a1 = fmaf(w1.y, v1.y, a1);
      a1 = fmaf(w1.z, v1.z, a1); a1 = fmaf(w1.w, v1.w, a1);
    }
    g2l[tid] = fmaxf(a0 + a1, 0.f);
  }
  __syncthreads();
  if (tid < 9) {
    float acc = bl[tid];
    for (int c = 0; c < 256; ++c) acc = fmaf(Wl[tid * 256 + c], g2l[c], acc);
    if (tid == 0 || tid == 4 || tid == 8) acc += 1.0f;
    out[b * 9 + tid] = acc;
  }
}

extern "C" void kernel_launch(void* const* d_in, const int* in_sizes, int n_in,
                              void* d_out, int out_size, void* d_ws, size_t ws_size,
                              hipStream_t stream) {
  const float* x   = (const float*)d_in[0];
  const float* W1  = (const float*)d_in[1];
  const float* b1  = (const float*)d_in[2];
  const float* W2  = (const float*)d_in[3];
  const float* b2  = (const float*)d_in[4];
  const float* Wi  = (const float*)d_in[5];
  const float* bi  = (const float*)d_in[6];
  const float* Wg1 = (const float*)d_in[7];
  const float* bg1 = (const float*)d_in[8];
  const float* Wg2 = (const float*)d_in[9];
  const float* bg2 = (const float*)d_in[10];
  const float* Wl  = (const float*)d_in[11];
  const float* bl  = (const float*)d_in[12];

  int*       knn = (int*)d_ws;                                   // 2.62 MB @ 0
  ushort_t*  hT  = (ushort_t*)((char*)d_ws + (3u << 20));        // 8 MB bf16
  ushort_t*  wiB = (ushort_t*)((char*)d_ws + (12u << 20));       // 256 KB bf16
  ushort_t*  w2B = (ushort_t*)((char*)d_ws + (12u << 20) + (512u << 10)); // 16 KB
  float4*    xT4 = (float4*)((char*)d_ws + (13u << 20));         // 512 KB
  unsigned*  g   = (unsigned*)((char*)d_ws + (14u << 20));       // 32 KB

  prep_kernel<<<128, 256, 0, stream>>>(x, xT4);
  knn_kernel<<<8 * NPTS / PPB, 256, 0, stream>>>(xT4, knn);
  convert_weights<<<512, 256, 0, stream>>>(Wi, W2, wiB, w2B);
  edge_fused<<<8 * NPTS / 8, 256, 0, stream>>>(xT4, knn, W1, b1, w2B, b2, hT);
  hipMemsetAsync(g, 0, 8 * 1024 * sizeof(unsigned), stream);
  inception_mfma<<<dim3(32, 8, 8), 256, 0, stream>>>(hT, wiB, bi, g);
  head_kernel<<<8, 512, 0, stream>>>(g, Wg1, bg1, Wg2, bg2, Wl, bl, (float*)d_out);
}

// Round 8
// 266.299 us; speedup vs baseline: 1.5302x; 1.2304x over previous
//
#include <hip/hip_runtime.h>
#include <stdint.h>

typedef unsigned long long u64;
typedef unsigned short ushort_t;
#define NPTS 4096
#define KNN 20

using bf16x8 = __attribute__((ext_vector_type(8))) short;
using f32x4  = __attribute__((ext_vector_type(4))) float;
using f32x2  = __attribute__((ext_vector_type(2))) float;

__device__ __forceinline__ unsigned orderbits(float f) {
  unsigned u = __float_as_uint(f);
  return ((int)u < 0) ? ~u : (u | 0x80000000u);
}

__device__ __forceinline__ ushort_t f2bf(float f) {  // RNE, finite inputs
  unsigned u = __float_as_uint(f);
  u += 0x7fffu + ((u >> 16) & 1u);
  return (ushort_t)(u >> 16);
}

__device__ __forceinline__ u64 shflxor64(u64 v, int m) {
  unsigned lo = __shfl_xor((unsigned)(v & 0xffffffffull), m, 64);
  unsigned hi = __shfl_xor((unsigned)(v >> 32), m, 64);
  return (((u64)hi) << 32) | lo;
}

// canonical reference-association distance (UNIQUE rounding sequence)
__device__ __forceinline__ float dist_exact(float4 q, float4 a) {
  float inner = __fadd_rn(__fadd_rn(__fmul_rn(q.x, a.x), __fmul_rn(q.y, a.y)),
                          __fmul_rn(q.z, a.z));
  return __fadd_rn(__fsub_rn(q.w, __fmul_rn(2.0f, inner)), a.w);
}

// packed 2-query distance: v_pk_mul/add_f32, contract(off) => each half is
// bit-identical to dist_exact (same ops, same association, RN, no fma)
__device__ __forceinline__ f32x2 dist2(f32x2 qx, f32x2 qy, f32x2 qz, f32x2 qw,
                                       float4 a) {
#pragma clang fp contract(off)
  f32x2 ax = {a.x, a.x}, ay = {a.y, a.y}, az = {a.z, a.z}, aw = {a.w, a.w};
  f32x2 t0 = qx * ax;
  f32x2 t1 = qy * ay;
  f32x2 t2 = qz * az;
  f32x2 inner = (t0 + t1) + t2;
  f32x2 two = {2.0f, 2.0f};
  return (qw - two * inner) + aw;
}

// monotone bucket via fp32 bit ordering; 512 buckets, 16 sub-buckets/octave,
// covers d in [2^-12, 2^20). 4 VALU ops.
__device__ __forceinline__ unsigned bucket_of(float d) {
  unsigned bits = __float_as_uint(fmaxf(d, 0.f));
  int t = (int)(bits >> 19) - 1840;            // 1840 = bits(2^-12)>>19
  return (unsigned)min(max(t, 0), 511);
}

// ---------------- Kernel 0: fused setup: xT4, Wi/W2->bf16, g=0 --------------
__global__ __launch_bounds__(256) void setup_kernel(
    const float* __restrict__ x, const float* __restrict__ Wi,
    const float* __restrict__ W2, float4* __restrict__ xT4,
    ushort_t* __restrict__ wiB, ushort_t* __restrict__ w2B,
    unsigned* __restrict__ g) {
  int i = blockIdx.x * 256 + threadIdx.x;  // grid 512*256 = 131072
  wiB[i] = f2bf(Wi[i]);
  if (i < 32768) {
    int b = i >> 12, m = i & 4095;
    const float* xb = x + (size_t)b * 3 * NPTS;
    float a0 = xb[m], a1 = xb[NPTS + m], a2 = xb[2 * NPTS + m];
    float sq = __fadd_rn(__fadd_rn(__fmul_rn(a0, a0), __fmul_rn(a1, a1)),
                         __fmul_rn(a2, a2));
    xT4[i] = make_float4(a0, a1, a2, sq);
  }
  if (i < 8192) { w2B[i] = f2bf(W2[i]); g[i] = 0u; }
}

// ---------------- Kernel 1: exact KNN, single-eval radix select -------------
#define NB 512
#define PPB 4
#define CCAP 128
__global__ __launch_bounds__(256) void knn_kernel(const float4* __restrict__ xT4,
                                                  int* __restrict__ knn_out) {
  __shared__ unsigned hist[PPB * NB];   // 8 KB
  __shared__ u64 cand[PPB * CCAP];      // 4 KB
  __shared__ unsigned sB[PPB], sCnt[PPB], sCand[PPB];

  const int tid = threadIdx.x;
  const int bid = blockIdx.x;           // 8192
  const int b = bid >> 10;
  const int n0 = (bid & 1023) * PPB;
  const float4* xb4 = xT4 + (size_t)b * NPTS;

  float4 q[PPB];
#pragma unroll
  for (int p = 0; p < PPB; ++p) q[p] = xb4[n0 + p];
  const f32x2 qx01 = {q[0].x, q[1].x}, qy01 = {q[0].y, q[1].y},
              qz01 = {q[0].z, q[1].z}, qw01 = {q[0].w, q[1].w};
  const f32x2 qx23 = {q[2].x, q[3].x}, qy23 = {q[2].y, q[3].y},
              qz23 = {q[2].z, q[3].z}, qw23 = {q[2].w, q[3].w};

  for (int i = tid; i < PPB * NB; i += 256) hist[i] = 0;
  if (tid < PPB) { sCnt[tid] = 0; sCand[tid] = 0; }
  __syncthreads();

  // loop 1: single evaluation (packed), u16 keys -> registers, histogram
  unsigned kL[16], kH[16];
#pragma unroll 4
  for (int it = 0; it < 16; ++it) {
    const int m = it * 256 + tid;
    float4 a = xb4[m];
    f32x2 d01 = dist2(qx01, qy01, qz01, qw01, a);
    f32x2 d23 = dist2(qx23, qy23, qz23, qw23, a);
    unsigned bk0 = bucket_of(d01[0]);
    unsigned bk1 = bucket_of(d01[1]);
    unsigned bk2 = bucket_of(d23[0]);
    unsigned bk3 = bucket_of(d23[1]);
    atomicAdd(&hist[0 * NB + bk0], 1u);
    atomicAdd(&hist[1 * NB + bk1], 1u);
    atomicAdd(&hist[2 * NB + bk2], 1u);
    atomicAdd(&hist[3 * NB + bk3], 1u);
    kL[it] = bk0 | (bk1 << 16);
    kH[it] = bk2 | (bk3 << 16);
  }
  __syncthreads();

  // scan: wave wv owns point wv's 512-bucket hist (8 buckets/lane)
  const int lane = tid & 63, wv = tid >> 6;
  {
    unsigned h[8]; unsigned local = 0;
    const int hb = wv * NB + lane * 8;
#pragma unroll
    for (int j = 0; j < 8; ++j) { h[j] = hist[hb + j]; local += h[j]; }
    unsigned incl = local;
    for (int off = 1; off < 64; off <<= 1) {
      unsigned v = __shfl_up(incl, off, 64);
      if (lane >= off) incl += v;
    }
    unsigned excl = incl - local;
    if (excl < KNN && incl >= KNN) {       // exactly one lane
      unsigned cum = excl;
#pragma unroll
      for (int j = 0; j < 8; ++j) {
        if (cum + h[j] >= KNN) { sB[wv] = lane * 8 + j; break; }
        cum += h[j];
      }
    }
  }
  __syncthreads();

  const unsigned B0 = sB[0], B1 = sB[1], B2 = sB[2], B3 = sB[3];
  // loop 2: classify from register keys; exact recompute only at boundary
  for (int it = 0; it < 16; ++it) {
    const int m = it * 256 + tid;
    unsigned ks[PPB];
    ks[0] = kL[it] & 0xffffu; ks[1] = kL[it] >> 16;
    ks[2] = kH[it] & 0xffffu; ks[3] = kH[it] >> 16;
    unsigned Bs[PPB] = {B0, B1, B2, B3};
#pragma unroll
    for (int p = 0; p < PPB; ++p) {
      if (ks[p] < Bs[p]) {
        unsigned s = atomicAdd(&sCnt[p], 1u);
        knn_out[((size_t)((b << 12) + n0 + p)) * KNN + s] = m;
      } else if (ks[p] == Bs[p]) {
        float d = dist_exact(q[p], xb4[m]);
        unsigned s = atomicAdd(&sCand[p], 1u);
        if (s < CCAP) cand[p * CCAP + s] = (((u64)orderbits(d)) << 32) | (unsigned)m;
      }
    }
  }
  __syncthreads();

  // boundary: wave wv extracts (20 - nsel) smallest (key,idx)
  {
    const int nsel = (int)sCnt[wv];
    const int ncand = min((int)sCand[wv], CCAP);
    const int ntake = KNN - nsel;
    const size_t base = ((size_t)((b << 12) + n0 + wv)) * KNN;
    volatile u64* vc = &cand[wv * CCAP];
    for (int t = 0; t < ntake; ++t) {
      u64 mk = ~0ull;
      for (int i = lane; i < ncand; i += 64) { u64 v = vc[i]; if (v < mk) mk = v; }
      for (int off = 32; off; off >>= 1) { u64 o = shflxor64(mk, off); if (o < mk) mk = o; }
      if (lane == 0) knn_out[base + nsel + t] = (int)(unsigned)(mk & 0xffffffffull);
      for (int i = lane; i < ncand; i += 64) { if (vc[i] == mk) vc[i] = ~0ull; }
    }
  }
}

// ---------------- Kernel 2: fused edge MLP 6->64->128 (MFMA) + max over K ---
// 4 points/block, 32 KB LDS -> 4-5 blocks/CU (2x occupancy vs 48 KB version).
// Threads 0-127: stage 1 (32 thr/point). Threads 128-255: stage W2 to LDS.
// Stage 2: wave wv computes point wv (2 A-tiles x 8 B-tiles MFMA, max fold).
__global__ __launch_bounds__(256, 4) void edge_fused(
    const float4* __restrict__ xT4, const int* __restrict__ knn,
    const float* __restrict__ W1, const float* __restrict__ b1,
    const ushort_t* __restrict__ w2B, const float* __restrict__ b2,
    ushort_t* __restrict__ hT) {
  __shared__ __align__(16) ushort_t h1S[4 * 32 * 64];  // 16 KB
  __shared__ __align__(16) ushort_t w2S[128 * 64];     // 16 KB, swizzled
  const int tid = threadIdx.x;
  const int lane = tid & 63, wv = tid >> 6;
  const int ln = lane & 15, quad = lane >> 4;

  if (tid < 128) {
    // ---- stage 1: h1 = relu(W1 @ edge + b1), 2 channels/thread, 20 edges
    const int p = tid >> 5, s5 = tid & 31;
    const int idx = blockIdx.x * 4 + p;
    const int b = idx >> 12, n = idx & 4095;
    const float4* xb4 = xT4 + ((size_t)b << 12);
    const float4 c4 = xb4[n];
    const int c0 = 2 * s5;
    float w1a[6], w1b[6];
#pragma unroll
    for (int j = 0; j < 6; ++j) {
      w1a[j] = W1[c0 * 6 + j];
      w1b[j] = W1[(c0 + 1) * 6 + j];
    }
    const float b1a = b1[c0], b1b = b1[c0 + 1];
    const int kbase = idx * KNN;
    unsigned* h1d = (unsigned*)h1S;
#pragma unroll 4
    for (int k = 0; k < KNN; ++k) {
      int nb = knn[kbase + k];
      float4 a4 = xb4[nb];
      float e3 = a4.x - c4.x, e4 = a4.y - c4.y, e5 = a4.z - c4.z;
      float za = b1a, zb = b1b;
      za = fmaf(w1a[0], c4.x, za); zb = fmaf(w1b[0], c4.x, zb);
      za = fmaf(w1a[1], c4.y, za); zb = fmaf(w1b[1], c4.y, zb);
      za = fmaf(w1a[2], c4.z, za); zb = fmaf(w1b[2], c4.z, zb);
      za = fmaf(w1a[3], e3, za);   zb = fmaf(w1b[3], e3, zb);
      za = fmaf(w1a[4], e4, za);   zb = fmaf(w1b[4], e4, zb);
      za = fmaf(w1a[5], e5, za);   zb = fmaf(w1b[5], e5, zb);
      unsigned pk = (unsigned)f2bf(fmaxf(za, 0.f)) |
                    ((unsigned)f2bf(fmaxf(zb, 0.f)) << 16);
      int row = p * 32 + k;
      int dw = row * 32 + (((s5 >> 2) ^ (row & 7)) << 2) + (s5 & 3);
      h1d[dw] = pk;
    }
  } else {
    // ---- W2 staging by threads 128..255: chunk c of row -> c^(row&7)
    const int t = tid - 128;
    const int4* wg = (const int4*)w2B;
#pragma unroll
    for (int j = 0; j < 8; ++j) {
      int qq = j * 128 + t;
      int row = qq >> 3, c = qq & 7;
      ((int4*)w2S)[row * 8 + (c ^ (row & 7))] = wg[qq];
    }
  }
  float b2r[8];
#pragma unroll
  for (int n = 0; n < 8; ++n) b2r[n] = b2[n * 16 + ln];
  __syncthreads();

  // B-fragments from swizzled LDS
  bf16x8 Bf[8][2];
#pragma unroll
  for (int n = 0; n < 8; ++n)
#pragma unroll
    for (int s = 0; s < 2; ++s) {
      int row = n * 16 + ln;
      Bf[n][s] = *(const bf16x8*)&w2S[row * 64 + (((s * 4 + quad) ^ (ln & 7)) << 3)];
    }

  // ---- stage 2: wave wv -> point wv; rows 20..31 garbage -> masked
  const int ps = wv;
  const int sw = ln & 7;
  float vmax[8];
  {  // tile 0: edge rows 0..15 (all real)
    const int row = ps * 32 + ln;
    bf16x8 A0 = *(const bf16x8*)&h1S[row * 64 + (((0 + quad) ^ sw) << 3)];
    bf16x8 A1 = *(const bf16x8*)&h1S[row * 64 + (((4 + quad) ^ sw) << 3)];
    f32x4 acc;
#pragma unroll
    for (int n = 0; n < 8; ++n) {
      acc = (f32x4){0.f, 0.f, 0.f, 0.f};
      acc = __builtin_amdgcn_mfma_f32_16x16x32_bf16(A0, Bf[n][0], acc, 0, 0, 0);
      acc = __builtin_amdgcn_mfma_f32_16x16x32_bf16(A1, Bf[n][1], acc, 0, 0, 0);
      vmax[n] = fmaxf(fmaxf(acc[0], acc[1]), fmaxf(acc[2], acc[3]));
    }
  }
  {  // tile 1: edge rows 16..31; real only 16..19 => quad==0 C rows
    const int row = ps * 32 + 16 + ln;
    bf16x8 A0 = *(const bf16x8*)&h1S[row * 64 + (((0 + quad) ^ sw) << 3)];
    bf16x8 A1 = *(const bf16x8*)&h1S[row * 64 + (((4 + quad) ^ sw) << 3)];
    f32x4 acc;
#pragma unroll
    for (int n = 0; n < 8; ++n) {
      acc = (f32x4){0.f, 0.f, 0.f, 0.f};
      acc = __builtin_amdgcn_mfma_f32_16x16x32_bf16(A0, Bf[n][0], acc, 0, 0, 0);
      acc = __builtin_amdgcn_mfma_f32_16x16x32_bf16(A1, Bf[n][1], acc, 0, 0, 0);
      float v1 = (quad == 0)
                     ? fmaxf(fmaxf(acc[0], acc[1]), fmaxf(acc[2], acc[3]))
                     : -INFINITY;
      vmax[n] = fmaxf(vmax[n], v1);
    }
  }
  const int gidx = blockIdx.x * 4 + ps;
#pragma unroll
  for (int n = 0; n < 8; ++n) {
    float v = vmax[n];
    v = fmaxf(v, __shfl_xor(v, 16, 64));
    v = fmaxf(v, __shfl_xor(v, 32, 64));
    if (quad == 0) {
      hT[(size_t)gidx * 128 + n * 16 + ln] = f2bf(fmaxf(v + b2r[n], 0.f));
    }
  }
}

// ---------------- Kernel 3: 128->1024 via bf16 MFMA + relu + max over N -----
#define LDP 136
__global__ __launch_bounds__(256, 2) void inception_mfma(
    const ushort_t* __restrict__ hT, const ushort_t* __restrict__ wiB,
    const float* __restrict__ bi, unsigned* __restrict__ g) {
  __shared__ __align__(16) ushort_t hS[128 * LDP];
  __shared__ __align__(16) ushort_t wS[128 * LDP];
  const int tid = threadIdx.x;
  const int b = blockIdx.z;
  const int m0 = blockIdx.x * 128;
  const int n0 = blockIdx.y * 128;

  const ushort_t* hg = hT + ((size_t)b * NPTS + m0) * 128;
  const ushort_t* wg = wiB + (size_t)n0 * 128;
#pragma unroll
  for (int i = 0; i < 8; ++i) {
    int chunk = i * 256 + tid;
    int row = chunk >> 4, c = chunk & 15;
    *(int4*)&hS[row * LDP + c * 8] = *(const int4*)&hg[row * 128 + c * 8];
    *(int4*)&wS[row * LDP + c * 8] = *(const int4*)&wg[row * 128 + c * 8];
  }
  __syncthreads();

  const int lane = tid & 63, wid = tid >> 6;
  const int ln = lane & 15, quad = lane >> 4;
  const int mw = (wid >> 1) * 64, nw = (wid & 1) * 64;

  f32x4 acc[4][4];
#pragma unroll
  for (int mi = 0; mi < 4; ++mi)
#pragma unroll
    for (int ni = 0; ni < 4; ++ni) acc[mi][ni] = (f32x4){0.f, 0.f, 0.f, 0.f};

#pragma unroll
  for (int kk = 0; kk < 4; ++kk) {
    bf16x8 af[4], bfr[4];
    const int ko = kk * 32 + quad * 8;
#pragma unroll
    for (int mi = 0; mi < 4; ++mi)
      af[mi] = *(const bf16x8*)&hS[(mw + mi * 16 + ln) * LDP + ko];
#pragma unroll
    for (int ni = 0; ni < 4; ++ni)
      bfr[ni] = *(const bf16x8*)&wS[(nw + ni * 16 + ln) * LDP + ko];
#pragma unroll
    for (int mi = 0; mi < 4; ++mi)
#pragma unroll
      for (int ni = 0; ni < 4; ++ni)
        acc[mi][ni] = __builtin_amdgcn_mfma_f32_16x16x32_bf16(
            af[mi], bfr[ni], acc[mi][ni], 0, 0, 0);
  }

#pragma unroll
  for (int ni = 0; ni < 4; ++ni) {
    float v = acc[0][ni][0];
#pragma unroll
    for (int mi = 0; mi < 4; ++mi)
#pragma unroll
      for (int r = 0; r < 4; ++r) v = fmaxf(v, acc[mi][ni][r]);
    v = fmaxf(v, __shfl_xor(v, 16, 64));
    v = fmaxf(v, __shfl_xor(v, 32, 64));
    if (quad == 0) {
      int o = n0 + nw + ni * 16 + ln;
      float val = fmaxf(v + bi[o], 0.f);
      atomicMax(&g[b * 1024 + o], __float_as_uint(val));
    }
  }
}

// ---------------- Kernel 4a: head layer1 1024->512 (64 blocks) --------------
__global__ __launch_bounds__(256) void head1_kernel(
    const unsigned* __restrict__ g, const float* __restrict__ Wg1,
    const float* __restrict__ bg1, float* __restrict__ g1) {
  const int b = blockIdx.x >> 3, slice = blockIdx.x & 7;
  const int tid = threadIdx.x;
  const int ol = tid >> 2, part = tid & 3;   // 64 outputs x 4 partials
  const int o = slice * 64 + ol;
  const float4* w = (const float4*)(Wg1 + (size_t)o * 1024 + part * 256);
  const float4* gv = (const float4*)((const float*)(g + b * 1024) + part * 256);
  float a0 = 0.f, a1 = 0.f, a2 = 0.f, a3 = 0.f;
#pragma unroll
  for (int j = 0; j < 64; j += 4) {
    float4 w0 = w[j], w1 = w[j+1], w2 = w[j+2], w3 = w[j+3];
    float4 v0 = gv[j], v1 = gv[j+1], v2 = gv[j+2], v3 = gv[j+3];
    a0 = fmaf(w0.x, v0.x, a0); a0 = fmaf(w0.y, v0.y, a0);
    a0 = fmaf(w0.z, v0.z, a0); a0 = fmaf(w0.w, v0.w, a0);
    a1 = fmaf(w1.x, v1.x, a1); a1 = fmaf(w1.y, v1.y, a1);
    a1 = fmaf(w1.z, v1.z, a1); a1 = fmaf(w1.w, v1.w, a1);
    a2 = fmaf(w2.x, v2.x, a2); a2 = fmaf(w2.y, v2.y, a2);
    a2 = fmaf(w2.z, v2.z, a2); a2 = fmaf(w2.w, v2.w, a2);
    a3 = fmaf(w3.x, v3.x, a3); a3 = fmaf(w3.y, v3.y, a3);
    a3 = fmaf(w3.z, v3.z, a3); a3 = fmaf(w3.w, v3.w, a3);
  }
  float s = (a0 + a1) + (a2 + a3);
  s += __shfl_xor(s, 1, 64);
  s += __shfl_xor(s, 2, 64);
  if (part == 0) g1[b * 512 + o] = fmaxf(s + bg1[o], 0.f);
}

// ---------------- Kernel 4b: head 512->256->9 + I ---------------------------
__global__ __launch_bounds__(256) void head2_kernel(
    const float* __restrict__ g1, const float* __restrict__ Wg2,
    const float* __restrict__ bg2, const float* __restrict__ Wl,
    const float* __restrict__ bl, float* __restrict__ out) {
  __shared__ __align__(16) float g1l[512];
  __shared__ __align__(16) float g2l[256];
  const int tid = threadIdx.x;
  const int b = blockIdx.x;
  g1l[tid] = g1[b * 512 + tid];
  g1l[tid + 256] = g1[b * 512 + 256 + tid];
  __syncthreads();
  {
    const float4* w = (const float4*)(Wg2 + (size_t)tid * 512);
    const float4* gv = (const float4*)g1l;
    float a0 = bg2[tid], a1 = 0.f;
    for (int j = 0; j < 128; j += 2) {
      float4 w0 = w[j], w1 = w[j+1];
      float4 v0 = gv[j], v1 = gv[j+1];
      a0 = fmaf(w0.x, v0.x, a0); a0 = fmaf(w0.y, v0.y, a0);
      a0 = fmaf(w0.z, v0.z, a0); a0 = fmaf(w0.w, v0.w, a0);
      a1 = fmaf(w1.x, v1.x, a1); a1 = fmaf(w1.y, v1.y, a1);
      a1 = fmaf(w1.z, v1.z, a1); a1 = fmaf(w1.w, v1.w, a1);
    }
    g2l[tid] = fmaxf(a0 + a1, 0.f);
  }
  __syncthreads();
  if (tid < 9) {
    float acc = bl[tid];
    for (int c = 0; c < 256; ++c) acc = fmaf(Wl[tid * 256 + c], g2l[c], acc);
    if (tid == 0 || tid == 4 || tid == 8) acc += 1.0f;
    out[b * 9 + tid] = acc;
  }
}

extern "C" void kernel_launch(void* const* d_in, const int* in_sizes, int n_in,
                              void* d_out, int out_size, void* d_ws, size_t ws_size,
                              hipStream_t stream) {
  const float* x   = (const float*)d_in[0];
  const float* W1  = (const float*)d_in[1];
  const float* b1  = (const float*)d_in[2];
  const float* W2  = (const float*)d_in[3];
  const float* b2  = (const float*)d_in[4];
  const float* Wi  = (const float*)d_in[5];
  const float* bi  = (const float*)d_in[6];
  const float* Wg1 = (const float*)d_in[7];
  const float* bg1 = (const float*)d_in[8];
  const float* Wg2 = (const float*)d_in[9];
  const float* bg2 = (const float*)d_in[10];
  const float* Wl  = (const float*)d_in[11];
  const float* bl  = (const float*)d_in[12];

  int*       knn = (int*)d_ws;                                   // 2.62 MB @ 0
  ushort_t*  hT  = (ushort_t*)((char*)d_ws + (3u << 20));        // 8 MB bf16
  ushort_t*  wiB = (ushort_t*)((char*)d_ws + (12u << 20));       // 256 KB bf16
  ushort_t*  w2B = (ushort_t*)((char*)d_ws + (12u << 20) + (512u << 10)); // 16 KB
  float4*    xT4 = (float4*)((char*)d_ws + (13u << 20));         // 512 KB
  unsigned*  g   = (unsigned*)((char*)d_ws + (14u << 20));       // 32 KB
  float*     g1  = (float*)((char*)d_ws + (14u << 20) + (64u << 10));     // 16 KB

  setup_kernel<<<512, 256, 0, stream>>>(x, Wi, W2, xT4, wiB, w2B, g);
  knn_kernel<<<8 * NPTS / PPB, 256, 0, stream>>>(xT4, knn);
  edge_fused<<<8 * NPTS / 4, 256, 0, stream>>>(xT4, knn, W1, b1, w2B, b2, hT);
  inception_mfma<<<dim3(32, 8, 8), 256, 0, stream>>>(hT, wiB, bi, g);
  head1_kernel<<<64, 256, 0, stream>>>(g, Wg1, bg1, g1);
  head2_kernel<<<8, 256, 0, stream>>>(g1, Wg2, bg2, Wl, bl, (float*)d_out);
}